// Round 15
// baseline (150.967 us; speedup 1.0000x reference)
//
#include <hip/hip_runtime.h>
#include <hip/hip_bf16.h>
#include <cstdint>
#include <cstddef>

// B=4, S=4096, D=1024, E=10, R=4, TOPK=2, SCALING=0.25
#define D_DIM 1024
#define E_NUM 10

typedef __attribute__((ext_vector_type(8))) short bf16x8;
typedef __attribute__((ext_vector_type(4))) float f32x4;
typedef unsigned short u16;
typedef unsigned int u32;

__device__ __forceinline__ u16 f2bf(float f) {
  union { float f; u32 u; } v; v.f = f;
  u32 r = v.u + 0x7fffu + ((v.u >> 16) & 1u);   // RNE
  return (u16)(r >> 16);
}
__device__ __forceinline__ float bf2f(u16 u) {
  union { u32 u; float f; } v; v.u = ((u32)u) << 16; return v.f;
}
__device__ __forceinline__ float dot4(float4 a, float4 b) {
  return a.x * b.x + a.y * b.y + a.z * b.z + a.w * b.w;
}

// ---------------- W_base fp32 -> bf16 (proven) ----------------
__global__ void conv_w(const float* __restrict__ W, u16* __restrict__ Wb) {
  const int i = (blockIdx.x * 256 + threadIdx.x) * 8;
  float4 a = *(const float4*)(W + i);
  float4 b = *(const float4*)(W + i + 4);
  *(ushort4*)(Wb + i)     = make_ushort4(f2bf(a.x), f2bf(a.y), f2bf(a.z), f2bf(a.w));
  *(ushort4*)(Wb + i + 4) = make_ushort4(f2bf(b.x), f2bf(b.y), f2bf(b.z), f2bf(b.w));
}

// ---------------- Bld[48][1024] bf16: rows 0-39 = lora_down, 40-47 = 0 ------
__global__ void prep_ldb(const float* __restrict__ ld, u16* __restrict__ Bld) {
  const int r = blockIdx.x;   // 48
  for (int c = threadIdx.x; c < D_DIM; c += 256)
    Bld[r * D_DIM + c] = (r < 40) ? f2bf(ld[r * D_DIM + c]) : (u16)0;
}

// ---------------- Ub[1024][64] bf16: Ub[o][j] = lup[j>>2][o][j&3], pad 0 ----
__global__ void prep_ub(const float* __restrict__ lup, u16* __restrict__ Ub) {
  const int g = blockIdx.x * 256 + threadIdx.x;   // 65536 threads
  const int o = g >> 6, j = g & 63;
  Ub[g] = (j < 40) ? f2bf(lup[(size_t)(j >> 2) * (D_DIM * 4) + o * 4 + (j & 3)]) : (u16)0;
}

// ---------------- h via MFMA, 4-way k-split across waves (R11-proven) -------
__global__ __launch_bounds__(256)
void moe_prep_h(const float* __restrict__ x, const u16* __restrict__ Bld,
                u16* __restrict__ hb, u16* __restrict__ xb) {
  __shared__ u16 sX[4][16 * 64];
  __shared__ u16 sB[4][48 * 64];
  __shared__ float sP[4][3][16][17];

  const int tid = threadIdx.x, lane = tid & 63, w = tid >> 6;
  const int r0 = blockIdx.x * 16;
  const int kbase = w * 256;

  f32x4 acc[3] = {};

  float4 av[4];
#pragma unroll
  for (int i = 0; i < 2; ++i) {
    const int c = lane * 2 + i, row = c >> 3, kc = c & 7;
    const float* g = x + (size_t)(r0 + row) * D_DIM + kbase + kc * 8;
    av[i * 2]     = *(const float4*)g;
    av[i * 2 + 1] = *(const float4*)(g + 4);
  }

#pragma unroll 1
  for (int kt = 0; kt < 4; ++kt) {
    const int k0 = kbase + kt * 64;
#pragma unroll
    for (int i = 0; i < 6; ++i) {
      const int c = i * 64 + lane, row = c >> 3, kc = (c & 7) ^ (row & 7);
      __builtin_amdgcn_global_load_lds(
          (const __attribute__((address_space(1))) u32*)(Bld + (size_t)row * D_DIM + k0 + kc * 8),
          (__attribute__((address_space(3))) u32*)&sB[w][c * 8], 16, 0, 0);
    }
#pragma unroll
    for (int i = 0; i < 2; ++i) {
      const int c = lane * 2 + i, row = c >> 3, kc = c & 7;
      const float4 a = av[i * 2], b = av[i * 2 + 1];
      const ushort4 ha  = make_ushort4(f2bf(a.x), f2bf(a.y), f2bf(a.z), f2bf(a.w));
      const ushort4 hb4 = make_ushort4(f2bf(b.x), f2bf(b.y), f2bf(b.z), f2bf(b.w));
      const int off = (row * 128 + kc * 16) ^ ((row & 7) << 4);
      *(ushort4*)((char*)sX[w] + off)     = ha;
      *(ushort4*)((char*)sX[w] + off + 8) = hb4;
      if (xb) {
        u16* dst = xb + (size_t)(r0 + row) * D_DIM + k0 + kc * 8;
        *(ushort4*)dst       = ha;
        *(ushort4*)(dst + 4) = hb4;
      }
    }
    __syncthreads();
    if (kt < 3) {
#pragma unroll
      for (int i = 0; i < 2; ++i) {
        const int c = lane * 2 + i, row = c >> 3, kc = c & 7;
        const float* g = x + (size_t)(r0 + row) * D_DIM + (k0 + 64) + kc * 8;
        av[i * 2]     = *(const float4*)g;
        av[i * 2 + 1] = *(const float4*)(g + 4);
      }
    }
#pragma unroll
    for (int kk = 0; kk < 2; ++kk) {
      const int kb = kk * 64 + ((lane >> 4) * 16);
      const int rA = lane & 15;
      const bf16x8 a0 = *(const bf16x8*)((const char*)sX[w] + ((rA * 128 + kb) ^ ((rA & 7) << 4)));
#pragma unroll
      for (int cf = 0; cf < 3; ++cf) {
        const int rB = cf * 16 + (lane & 15);
        const bf16x8 q = *(const bf16x8*)((const char*)sB[w] + ((rB * 128 + kb) ^ ((rB & 7) << 4)));
        acc[cf] = __builtin_amdgcn_mfma_f32_16x16x32_bf16(a0, q, acc[cf], 0, 0, 0);
      }
    }
    __syncthreads();
  }

#pragma unroll
  for (int cf = 0; cf < 3; ++cf)
#pragma unroll
    for (int j = 0; j < 4; ++j)
      sP[w][cf][(lane >> 4) * 4 + j][lane & 15] = acc[cf][j];
  __syncthreads();

  const int row = tid >> 4, c16 = tid & 15;
#pragma unroll
  for (int cf = 0; cf < 3; ++cf) {
    const int col = cf * 16 + c16;
    if (col < 40) {
      const float s = sP[0][cf][row][c16] + sP[1][cf][row][c16] +
                      sP[2][cf][row][c16] + sP[3][cf][row][c16];
      hb[(size_t)(r0 + row) * 40 + col] = f2bf(s);
    }
  }
}

// ---------------- gate3 (R14-proven): 16 tok/block, zero shuffles -----------
__global__ __launch_bounds__(256)
void moe_gate3(const float* __restrict__ x, const float* __restrict__ gW,
               const float* __restrict__ gb, const u16* __restrict__ hb,
               u16* __restrict__ cd) {
  __shared__ char  sRaw[4][4096];
  __shared__ float sPart[16 * 16 * 11];

  const int tid = threadIdx.x, lane = tid & 63, w = tid >> 6;
  const int r0 = blockIdx.x * 16;
  const int kq = w * 256;
  const int t = lane & 15, s = lane >> 4;

  float acc[E_NUM] = {};

  float4 pv[4];
#pragma unroll
  for (int i = 0; i < 4; ++i) {
    const int f = i * 64 + lane, tok = f >> 4, g = f & 15;
    pv[i] = *(const float4*)(x + (size_t)(r0 + tok) * D_DIM + kq + g * 4);
  }

#pragma unroll 1
  for (int c = 0; c < 4; ++c) {
    const int k0 = kq + c * 64;
#pragma unroll
    for (int i = 0; i < 4; ++i) {
      const int f = i * 64 + lane, tok = f >> 4, g = f & 15;
      *(float4*)(sRaw[w] + tok * 256 + ((g ^ (tok & 15)) << 4)) = pv[i];
    }
    float4 xr[4];
#pragma unroll
    for (int j = 0; j < 4; ++j) {
      const int g = s * 4 + j;
      xr[j] = *(const float4*)(sRaw[w] + t * 256 + ((g ^ (t & 15)) << 4));
    }
    if (c < 3) {
#pragma unroll
      for (int i = 0; i < 4; ++i) {
        const int f = i * 64 + lane, tok = f >> 4, g = f & 15;
        pv[i] = *(const float4*)(x + (size_t)(r0 + tok) * D_DIM + (k0 + 64) + g * 4);
      }
    }
    const float* gwk = gW + k0 + s * 16;
#pragma unroll
    for (int e = 0; e < E_NUM; ++e) {
      float v = acc[e];
#pragma unroll
      for (int j = 0; j < 4; ++j)
        v += dot4(xr[j], *(const float4*)(gwk + e * D_DIM + j * 4));
      acc[e] = v;
    }
  }

  {
    float* dst = sPart + ((w * 4 + s) * 16 + t) * 11;
#pragma unroll
    for (int e = 0; e < E_NUM; ++e) dst[e] = acc[e];
  }
  __syncthreads();

  if (tid < 16) {
    const int tok = tid, tt = r0 + tok;
    float lg[E_NUM];
#pragma unroll
    for (int e = 0; e < E_NUM; ++e) {
      float v = gb[e];
#pragma unroll
      for (int p = 0; p < 16; ++p) v += sPart[(p * 16 + tok) * 11 + e];
      lg[e] = v;
    }
    int e0 = 0; float v0 = lg[0];
#pragma unroll
    for (int e = 1; e < E_NUM; ++e) if (lg[e] > v0) { v0 = lg[e]; e0 = e; }
    int e1 = -1; float v1 = -3.0e38f;
#pragma unroll
    for (int e = 0; e < E_NUM; ++e) if (e != e0 && lg[e] > v1) { v1 = lg[e]; e1 = e; }
    const float pp = expf(v1 - v0);
    const float inv = 1.f / (1.f + pp);
    const float s0 = inv * 0.25f, s1 = pp * inv * 0.25f;   // softmax * SCALING

    u16* dst = cd + (size_t)tt * 64;
    const u16* hrow = hb + (size_t)tt * 40;
#pragma unroll
    for (int e = 0; e < E_NUM; ++e) {
      const float we = (e == e0) ? s0 : ((e == e1) ? s1 : 0.f);
      const ushort4 hh = *(const ushort4*)(hrow + e * 4);
      *(ushort4*)(dst + e * 4) = make_ushort4(
          f2bf(bf2f(hh.x) * we), f2bf(bf2f(hh.y) * we),
          f2bf(bf2f(hh.z) * we), f2bf(bf2f(hh.w) * we));
    }
#pragma unroll
    for (int j = 40; j < 64; j += 4)
      *(ushort4*)(dst + j) = make_ushort4(0, 0, 0, 0);
  }
}

// ---------------- main GEMM: 256x256, 8 waves, counted-vmcnt pipeline -------
// Per K-tile: reads(af0,bfr) -> 32 MFMA -> reads(af1) -> lgkmcnt(0) -> barrier
// -> STAGE(kt+2 into just-freed buffer) -> 32 MFMA -> vmcnt(8) -> barrier.
// vmcnt never drains to 0 in steady state; per-wave vmcnt(8) before the
// all-wave barrier guarantees every wave's kt+1 stages retired before any
// wave reads them (in-order VMEM retirement).
__global__ __launch_bounds__(512, 2)
void moe_gemm_8p(const u16* __restrict__ xb, const u16* __restrict__ Wbf,
                 const u16* __restrict__ cd, const u16* __restrict__ Ub,
                 const float* __restrict__ bias, float* __restrict__ out) {
  __shared__ u16 Al[2][256 * 64];   // 2 x 32 KB
  __shared__ u16 Bl[2][256 * 64];   // 2 x 32 KB

  const int tid = threadIdx.x, lane = tid & 63, wid = tid >> 6;
  const int wm = wid >> 2, wn = wid & 3;          // 2 x 4 wave grid
  const int p = blockIdx.x;                        // 256 blocks = 1/CU
  const int cx = p & 7, q = p >> 3;
  const int nb = q & 3, mb = cx * 8 + (q >> 2);    // XCD: 8 mb x all 4 nb
  const int m0 = mb * 256, n0 = nb * 256;

  // stage ownership: wm-group stages its A-half; wn-pair group its B-half
  const int hA = tid >> 8;                         // 0/1 (waves 0-3 / 4-7)
  const int ltA = tid & 255;
  const int hB = (wid >> 1) & 1;                   // B-half0: wid {0,1,4,5}
  const int ltB = ((wid >> 2) * 2 + (wid & 1)) * 64 + lane;

  f32x4 acc[8][4] = {};

  auto STAGE = [&](int buf, int ktile) {
#pragma unroll
    for (int i = 0; i < 4; ++i) {
      const int c = i * 256 + ltA, row = c >> 3, kc = (c & 7) ^ (row & 7);
      const u16* src = (ktile < 16)
          ? xb + (size_t)(m0 + hA * 128 + row) * D_DIM + ktile * 64 + kc * 8
          : cd + (size_t)(m0 + hA * 128 + row) * 64 + kc * 8;
      __builtin_amdgcn_global_load_lds(
          (const __attribute__((address_space(1))) u32*)src,
          (__attribute__((address_space(3))) u32*)&Al[buf][hA * 8192 + c * 8], 16, 0, 0);
    }
#pragma unroll
    for (int i = 0; i < 4; ++i) {
      const int c = i * 256 + ltB, row = c >> 3, kc = (c & 7) ^ (row & 7);
      const u16* src = (ktile < 16)
          ? Wbf + (size_t)(n0 + hB * 128 + row) * D_DIM + ktile * 64 + kc * 8
          : Ub + (size_t)(n0 + hB * 128 + row) * 64 + kc * 8;
      __builtin_amdgcn_global_load_lds(
          (const __attribute__((address_space(1))) u32*)src,
          (__attribute__((address_space(3))) u32*)&Bl[buf][hB * 8192 + c * 8], 16, 0, 0);
    }
  };

  STAGE(0, 0);
  STAGE(1, 1);                                     // 16 loads in flight
  asm volatile("s_waitcnt vmcnt(8)" ::: "memory"); // kt0's 8 retired
  __builtin_amdgcn_s_barrier();

#pragma unroll 1
  for (int kt = 0; kt < 17; ++kt) {
    const int cur = kt & 1;
    const int kbq = (lane >> 4) * 16;

    // ---- group A: bfr (all n) + af for m 0..3; 32 MFMA ----
    bf16x8 bfr[4][2], af0[4][2];
#pragma unroll
    for (int n = 0; n < 4; ++n) {
      const int row = wn * 64 + n * 16 + (lane & 15);
#pragma unroll
      for (int kk = 0; kk < 2; ++kk)
        bfr[n][kk] = *(const bf16x8*)((const char*)Bl[cur] +
                        ((row * 128 + kk * 64 + kbq) ^ ((row & 7) << 4)));
    }
#pragma unroll
    for (int m = 0; m < 4; ++m) {
      const int row = wm * 128 + m * 16 + (lane & 15);
#pragma unroll
      for (int kk = 0; kk < 2; ++kk)
        af0[m][kk] = *(const bf16x8*)((const char*)Al[cur] +
                        ((row * 128 + kk * 64 + kbq) ^ ((row & 7) << 4)));
    }
#pragma unroll
    for (int kk = 0; kk < 2; ++kk)
#pragma unroll
      for (int m = 0; m < 4; ++m)
#pragma unroll
        for (int n = 0; n < 4; ++n)
          acc[m][n] = __builtin_amdgcn_mfma_f32_16x16x32_bf16(af0[m][kk], bfr[n][kk], acc[m][n], 0, 0, 0);

    // ---- group B reads: af for m 4..7 ----
    bf16x8 af1[4][2];
#pragma unroll
    for (int m = 0; m < 4; ++m) {
      const int row = wm * 128 + (m + 4) * 16 + (lane & 15);
#pragma unroll
      for (int kk = 0; kk < 2; ++kk)
        af1[m][kk] = *(const bf16x8*)((const char*)Al[cur] +
                        ((row * 128 + kk * 64 + kbq) ^ ((row & 7) << 4)));
    }
    asm volatile("s_waitcnt lgkmcnt(0)" ::: "memory");   // all buf[cur] reads done
    __builtin_amdgcn_sched_barrier(0);
    __builtin_amdgcn_s_barrier();                        // every wave done reading
    if (kt + 2 <= 16) STAGE(cur, kt + 2);                // overwrite freed buffer

    __builtin_amdgcn_s_setprio(1);
#pragma unroll
    for (int kk = 0; kk < 2; ++kk)
#pragma unroll
      for (int m = 0; m < 4; ++m)
#pragma unroll
        for (int n = 0; n < 4; ++n)
          acc[m + 4][n] = __builtin_amdgcn_mfma_f32_16x16x32_bf16(af1[m][kk], bfr[n][kk], acc[m + 4][n], 0, 0, 0);
    __builtin_amdgcn_s_setprio(0);

    if (kt < 15)      { asm volatile("s_waitcnt vmcnt(8)" ::: "memory"); }
    else if (kt < 16) { asm volatile("s_waitcnt vmcnt(0)" ::: "memory"); }
    __builtin_amdgcn_sched_barrier(0);
    __builtin_amdgcn_s_barrier();
  }

  // ---- epilogue: bias only, fp32 store ----
  const int rg = lane >> 4, cl = lane & 15;
  const int baser = m0 + wm * 128, basec = n0 + wn * 64;
  float bs[4];
#pragma unroll
  for (int n = 0; n < 4; ++n) bs[n] = bias[basec + n * 16 + cl];
#pragma unroll
  for (int m = 0; m < 8; ++m)
#pragma unroll
    for (int j = 0; j < 4; ++j) {
      const int rr = baser + m * 16 + rg * 4 + j;
#pragma unroll
      for (int n = 0; n < 4; ++n)
        out[(size_t)rr * D_DIM + basec + n * 16 + cl] = acc[m][n][j] + bs[n];
    }
}

extern "C" void kernel_launch(void* const* d_in, const int* in_sizes, int n_in,
                              void* d_out, int out_size, void* d_ws, size_t ws_size,
                              hipStream_t stream) {
  const float* x   = (const float*)d_in[0];
  const float* Wb_ = (const float*)d_in[1];
  const float* bb  = (const float*)d_in[2];
  const float* gW  = (const float*)d_in[3];
  const float* gb  = (const float*)d_in[4];
  const float* ld  = (const float*)d_in[5];
  const float* lup = (const float*)d_in[6];

  // ws (KB): Wbf 0-2048 | Ub 2048-2176 | Bld 2176-2272 | cd 2272-4320 |
  //          hb 4320-5600 | xb 5600-38368  (within the proven 38400 KB bound)
  char* w = (char*)d_ws;
  u16* Wbf = (u16*)w;
  u16* Ub  = (u16*)(w + 2048ull * 1024);
  u16* Bld = (u16*)(w + 2176ull * 1024);
  u16* cd  = (u16*)(w + 2272ull * 1024);
  u16* hb  = (u16*)(w + 4320ull * 1024);
  u16* xb  = (u16*)(w + 5600ull * 1024);

  hipLaunchKernelGGL(conv_w,     dim3(512),  dim3(256), 0, stream, Wb_, Wbf);
  hipLaunchKernelGGL(prep_ldb,   dim3(48),   dim3(256), 0, stream, ld, Bld);
  hipLaunchKernelGGL(prep_ub,    dim3(256),  dim3(256), 0, stream, lup, Ub);
  hipLaunchKernelGGL(moe_prep_h, dim3(1024), dim3(256), 0, stream, x, Bld, hb, xb);
  hipLaunchKernelGGL(moe_gate3,  dim3(1024), dim3(256), 0, stream, x, gW, gb, hb, cd);
  hipLaunchKernelGGL(moe_gemm_8p, dim3(256), dim3(512), 0, stream,
                     xb, Wbf, cd, Ub, bb, (float*)d_out);
}

// Round 16
// 118.897 us; speedup vs baseline: 1.2697x; 1.2697x over previous
//
#include <hip/hip_runtime.h>
#include <hip/hip_bf16.h>
#include <cstdint>
#include <cstddef>

// B=4, S=4096, D=1024, E=10, R=4, TOPK=2, SCALING=0.25
#define D_DIM 1024
#define E_NUM 10

typedef __attribute__((ext_vector_type(8))) short bf16x8;
typedef __attribute__((ext_vector_type(4))) float f32x4;
typedef unsigned short u16;
typedef unsigned int u32;

__device__ __forceinline__ u16 f2bf(float f) {
  union { float f; u32 u; } v; v.f = f;
  u32 r = v.u + 0x7fffu + ((v.u >> 16) & 1u);   // RNE
  return (u16)(r >> 16);
}
__device__ __forceinline__ float bf2f(u16 u) {
  union { u32 u; float f; } v; v.u = ((u32)u) << 16; return v.f;
}
__device__ __forceinline__ float dot4(float4 a, float4 b) {
  return a.x * b.x + a.y * b.y + a.z * b.z + a.w * b.w;
}

// ---------------- fused W-prep: conv_w | Bld | Ub in one dispatch ----------
// blocks 0-511: W_base fp32->bf16 (Wbf). 512-559: Bld. 560-815: Ub.
__global__ void prep_w(const float* __restrict__ W, const float* __restrict__ ld,
                       const float* __restrict__ lup, u16* __restrict__ Wbf,
                       u16* __restrict__ Bld, u16* __restrict__ Ub) {
  const int bid = blockIdx.x, tid = threadIdx.x;
  if (bid < 512) {
    const int i = (bid * 256 + tid) * 8;
    float4 a = *(const float4*)(W + i);
    float4 b = *(const float4*)(W + i + 4);
    *(ushort4*)(Wbf + i)     = make_ushort4(f2bf(a.x), f2bf(a.y), f2bf(a.z), f2bf(a.w));
    *(ushort4*)(Wbf + i + 4) = make_ushort4(f2bf(b.x), f2bf(b.y), f2bf(b.z), f2bf(b.w));
  } else if (bid < 560) {
    const int r = bid - 512;      // 48 rows
    for (int c = tid; c < D_DIM; c += 256)
      Bld[r * D_DIM + c] = (r < 40) ? f2bf(ld[r * D_DIM + c]) : (u16)0;
  } else {
    const int g = (bid - 560) * 256 + tid;   // 65536 elems
    const int o = g >> 6, j = g & 63;
    Ub[g] = (j < 40) ? f2bf(lup[(size_t)(j >> 2) * (D_DIM * 4) + o * 4 + (j & 3)]) : (u16)0;
  }
}

// ---------------- h via MFMA, 4-way k-split across waves (R11-proven) -------
__global__ __launch_bounds__(256)
void moe_prep_h(const float* __restrict__ x, const u16* __restrict__ Bld,
                u16* __restrict__ hb, u16* __restrict__ xb) {
  __shared__ u16 sX[4][16 * 64];
  __shared__ u16 sB[4][48 * 64];
  __shared__ float sP[4][3][16][17];

  const int tid = threadIdx.x, lane = tid & 63, w = tid >> 6;
  const int r0 = blockIdx.x * 16;
  const int kbase = w * 256;

  f32x4 acc[3] = {};

  float4 av[4];
#pragma unroll
  for (int i = 0; i < 2; ++i) {
    const int c = lane * 2 + i, row = c >> 3, kc = c & 7;
    const float* g = x + (size_t)(r0 + row) * D_DIM + kbase + kc * 8;
    av[i * 2]     = *(const float4*)g;
    av[i * 2 + 1] = *(const float4*)(g + 4);
  }

#pragma unroll 1
  for (int kt = 0; kt < 4; ++kt) {
    const int k0 = kbase + kt * 64;
#pragma unroll
    for (int i = 0; i < 6; ++i) {
      const int c = i * 64 + lane, row = c >> 3, kc = (c & 7) ^ (row & 7);
      __builtin_amdgcn_global_load_lds(
          (const __attribute__((address_space(1))) u32*)(Bld + (size_t)row * D_DIM + k0 + kc * 8),
          (__attribute__((address_space(3))) u32*)&sB[w][c * 8], 16, 0, 0);
    }
#pragma unroll
    for (int i = 0; i < 2; ++i) {
      const int c = lane * 2 + i, row = c >> 3, kc = c & 7;
      const float4 a = av[i * 2], b = av[i * 2 + 1];
      const ushort4 ha  = make_ushort4(f2bf(a.x), f2bf(a.y), f2bf(a.z), f2bf(a.w));
      const ushort4 hb4 = make_ushort4(f2bf(b.x), f2bf(b.y), f2bf(b.z), f2bf(b.w));
      const int off = (row * 128 + kc * 16) ^ ((row & 7) << 4);
      *(ushort4*)((char*)sX[w] + off)     = ha;
      *(ushort4*)((char*)sX[w] + off + 8) = hb4;
      if (xb) {
        u16* dst = xb + (size_t)(r0 + row) * D_DIM + k0 + kc * 8;
        *(ushort4*)dst       = ha;
        *(ushort4*)(dst + 4) = hb4;
      }
    }
    __syncthreads();
    if (kt < 3) {
#pragma unroll
      for (int i = 0; i < 2; ++i) {
        const int c = lane * 2 + i, row = c >> 3, kc = c & 7;
        const float* g = x + (size_t)(r0 + row) * D_DIM + (k0 + 64) + kc * 8;
        av[i * 2]     = *(const float4*)g;
        av[i * 2 + 1] = *(const float4*)(g + 4);
      }
    }
#pragma unroll
    for (int kk = 0; kk < 2; ++kk) {
      const int kb = kk * 64 + ((lane >> 4) * 16);
      const int rA = lane & 15;
      const bf16x8 a0 = *(const bf16x8*)((const char*)sX[w] + ((rA * 128 + kb) ^ ((rA & 7) << 4)));
#pragma unroll
      for (int cf = 0; cf < 3; ++cf) {
        const int rB = cf * 16 + (lane & 15);
        const bf16x8 q = *(const bf16x8*)((const char*)sB[w] + ((rB * 128 + kb) ^ ((rB & 7) << 4)));
        acc[cf] = __builtin_amdgcn_mfma_f32_16x16x32_bf16(a0, q, acc[cf], 0, 0, 0);
      }
    }
    __syncthreads();
  }

#pragma unroll
  for (int cf = 0; cf < 3; ++cf)
#pragma unroll
    for (int j = 0; j < 4; ++j)
      sP[w][cf][(lane >> 4) * 4 + j][lane & 15] = acc[cf][j];
  __syncthreads();

  const int row = tid >> 4, c16 = tid & 15;
#pragma unroll
  for (int cf = 0; cf < 3; ++cf) {
    const int col = cf * 16 + c16;
    if (col < 40) {
      const float s = sP[0][cf][row][c16] + sP[1][cf][row][c16] +
                      sP[2][cf][row][c16] + sP[3][cf][row][c16];
      hb[(size_t)(r0 + row) * 40 + col] = f2bf(s);
    }
  }
}

// ---------------- gate3 (R14-proven): 16 tok/block, zero shuffles -----------
__global__ __launch_bounds__(256)
void moe_gate3(const float* __restrict__ x, const float* __restrict__ gW,
               const float* __restrict__ gb, const u16* __restrict__ hb,
               u16* __restrict__ cd) {
  __shared__ char  sRaw[4][4096];
  __shared__ float sPart[16 * 16 * 11];

  const int tid = threadIdx.x, lane = tid & 63, w = tid >> 6;
  const int r0 = blockIdx.x * 16;
  const int kq = w * 256;
  const int t = lane & 15, s = lane >> 4;

  float acc[E_NUM] = {};

  float4 pv[4];
#pragma unroll
  for (int i = 0; i < 4; ++i) {
    const int f = i * 64 + lane, tok = f >> 4, g = f & 15;
    pv[i] = *(const float4*)(x + (size_t)(r0 + tok) * D_DIM + kq + g * 4);
  }

#pragma unroll 1
  for (int c = 0; c < 4; ++c) {
    const int k0 = kq + c * 64;
#pragma unroll
    for (int i = 0; i < 4; ++i) {
      const int f = i * 64 + lane, tok = f >> 4, g = f & 15;
      *(float4*)(sRaw[w] + tok * 256 + ((g ^ (tok & 15)) << 4)) = pv[i];
    }
    float4 xr[4];
#pragma unroll
    for (int j = 0; j < 4; ++j) {
      const int g = s * 4 + j;
      xr[j] = *(const float4*)(sRaw[w] + t * 256 + ((g ^ (t & 15)) << 4));
    }
    if (c < 3) {
#pragma unroll
      for (int i = 0; i < 4; ++i) {
        const int f = i * 64 + lane, tok = f >> 4, g = f & 15;
        pv[i] = *(const float4*)(x + (size_t)(r0 + tok) * D_DIM + (k0 + 64) + g * 4);
      }
    }
    const float* gwk = gW + k0 + s * 16;
#pragma unroll
    for (int e = 0; e < E_NUM; ++e) {
      float v = acc[e];
#pragma unroll
      for (int j = 0; j < 4; ++j)
        v += dot4(xr[j], *(const float4*)(gwk + e * D_DIM + j * 4));
      acc[e] = v;
    }
  }

  {
    float* dst = sPart + ((w * 4 + s) * 16 + t) * 11;
#pragma unroll
    for (int e = 0; e < E_NUM; ++e) dst[e] = acc[e];
  }
  __syncthreads();

  if (tid < 16) {
    const int tok = tid, tt = r0 + tok;
    float lg[E_NUM];
#pragma unroll
    for (int e = 0; e < E_NUM; ++e) {
      float v = gb[e];
#pragma unroll
      for (int p = 0; p < 16; ++p) v += sPart[(p * 16 + tok) * 11 + e];
      lg[e] = v;
    }
    int e0 = 0; float v0 = lg[0];
#pragma unroll
    for (int e = 1; e < E_NUM; ++e) if (lg[e] > v0) { v0 = lg[e]; e0 = e; }
    int e1 = -1; float v1 = -3.0e38f;
#pragma unroll
    for (int e = 0; e < E_NUM; ++e) if (e != e0 && lg[e] > v1) { v1 = lg[e]; e1 = e; }
    const float pp = expf(v1 - v0);
    const float inv = 1.f / (1.f + pp);
    const float s0 = inv * 0.25f, s1 = pp * inv * 0.25f;   // softmax * SCALING

    u16* dst = cd + (size_t)tt * 64;
    const u16* hrow = hb + (size_t)tt * 40;
#pragma unroll
    for (int e = 0; e < E_NUM; ++e) {
      const float we = (e == e0) ? s0 : ((e == e1) ? s1 : 0.f);
      const ushort4 hh = *(const ushort4*)(hrow + e * 4);
      *(ushort4*)(dst + e * 4) = make_ushort4(
          f2bf(bf2f(hh.x) * we), f2bf(bf2f(hh.y) * we),
          f2bf(bf2f(hh.z) * we), f2bf(bf2f(hh.w) * we));
    }
#pragma unroll
    for (int j = 40; j < 64; j += 4)
      *(ushort4*)(dst + j) = make_ushort4(0, 0, 0, 0);
  }
}

// ---------------- main GEMM: K = 16 tiles (x@W^T) + 1 tail tile (cd@U^T) ----
// (R14-proven, best measured: 57.5 us) 2ph double-buffered; epilogue = bias.
__global__ __launch_bounds__(256, 2)
void moe_gemm_t(const u16* __restrict__ xb, const u16* __restrict__ Wbf,
                const u16* __restrict__ cd, const u16* __restrict__ Ub,
                const float* __restrict__ bias, float* __restrict__ out) {
  __shared__ u16 Al[2][128 * 64];
  __shared__ u16 Bl[2][128 * 64];

  const int tid = threadIdx.x, lane = tid & 63, wid = tid >> 6;
  const int wm = wid >> 1, wn = wid & 1;
  const int p = blockIdx.x;
  const int cx = p & 7, q = p >> 3;
  const int nb = q & 7, mb = cx * 16 + (q >> 3);
  const int m0 = mb * 128, n0 = nb * 128;

  int sc_row[4], sc_kc[4];
#pragma unroll
  for (int i = 0; i < 4; ++i) {
    const int c = i * 256 + tid;
    sc_row[i] = c >> 3;
    sc_kc[i]  = (c & 7) ^ (sc_row[i] & 7);
  }

  f32x4 acc[4][4] = {};

  auto STAGE = [&](int buf, int ktile) {
    const u16* As; const u16* Bs; size_t str; int ko;
    if (ktile < 16) {
      As = xb + (size_t)m0 * D_DIM; Bs = Wbf + (size_t)n0 * D_DIM;
      str = D_DIM; ko = ktile * 64;
    } else {
      As = cd + (size_t)m0 * 64; Bs = Ub + (size_t)n0 * 64;
      str = 64; ko = 0;
    }
#pragma unroll
    for (int i = 0; i < 4; ++i) {
      const int c = i * 256 + tid;
      __builtin_amdgcn_global_load_lds(
          (const __attribute__((address_space(1))) u32*)(As + (size_t)sc_row[i] * str + ko + sc_kc[i] * 8),
          (__attribute__((address_space(3))) u32*)&Al[buf][c * 8], 16, 0, 0);
    }
#pragma unroll
    for (int i = 0; i < 4; ++i) {
      const int c = i * 256 + tid;
      __builtin_amdgcn_global_load_lds(
          (const __attribute__((address_space(1))) u32*)(Bs + (size_t)sc_row[i] * str + ko + sc_kc[i] * 8),
          (__attribute__((address_space(3))) u32*)&Bl[buf][c * 8], 16, 0, 0);
    }
  };

  STAGE(0, 0);
  __syncthreads();

#pragma unroll 1
  for (int kt = 0; kt < 17; ++kt) {
    const int cur = kt & 1;
    if (kt < 16) STAGE(cur ^ 1, kt + 1);
#pragma unroll
    for (int kk = 0; kk < 2; ++kk) {
      bf16x8 af[4], bfr[4];
      const int kb = kk * 64 + ((lane >> 4) * 16);
#pragma unroll
      for (int m = 0; m < 4; ++m) {
        const int row = wm * 64 + m * 16 + (lane & 15);
        af[m] = *(const bf16x8*)((const char*)Al[cur] + ((row * 128 + kb) ^ ((row & 7) << 4)));
      }
#pragma unroll
      for (int n = 0; n < 4; ++n) {
        const int row = wn * 64 + n * 16 + (lane & 15);
        bfr[n] = *(const bf16x8*)((const char*)Bl[cur] + ((row * 128 + kb) ^ ((row & 7) << 4)));
      }
#pragma unroll
      for (int m = 0; m < 4; ++m)
#pragma unroll
        for (int n = 0; n < 4; ++n)
          acc[m][n] = __builtin_amdgcn_mfma_f32_16x16x32_bf16(af[m], bfr[n], acc[m][n], 0, 0, 0);
    }
    __syncthreads();
  }

  const int rg = lane >> 4, cl = lane & 15;
  const int baser = m0 + wm * 64, basec = n0 + wn * 64;
  float bs[4];
#pragma unroll
  for (int n = 0; n < 4; ++n) bs[n] = bias[basec + n * 16 + cl];
#pragma unroll
  for (int m = 0; m < 4; ++m)
#pragma unroll
    for (int j = 0; j < 4; ++j) {
      const int rr = baser + m * 16 + rg * 4 + j;
#pragma unroll
      for (int n = 0; n < 4; ++n)
        out[(size_t)rr * D_DIM + basec + n * 16 + cl] = acc[m][n][j] + bs[n];
    }
}

extern "C" void kernel_launch(void* const* d_in, const int* in_sizes, int n_in,
                              void* d_out, int out_size, void* d_ws, size_t ws_size,
                              hipStream_t stream) {
  const float* x   = (const float*)d_in[0];
  const float* Wb_ = (const float*)d_in[1];
  const float* bb  = (const float*)d_in[2];
  const float* gW  = (const float*)d_in[3];
  const float* gb  = (const float*)d_in[4];
  const float* ld  = (const float*)d_in[5];
  const float* lup = (const float*)d_in[6];

  // ws (KB): Wbf 0-2048 | Ub 2048-2176 | Bld 2176-2272 | cd 2272-4320 |
  //          hb 4320-5600 | xb 5600-38368
  char* w = (char*)d_ws;
  u16* Wbf = (u16*)w;
  u16* Ub  = (u16*)(w + 2048ull * 1024);
  u16* Bld = (u16*)(w + 2176ull * 1024);
  u16* cd  = (u16*)(w + 2272ull * 1024);
  u16* hb  = (u16*)(w + 4320ull * 1024);
  u16* xb  = (u16*)(w + 5600ull * 1024);

  hipLaunchKernelGGL(prep_w,     dim3(816),  dim3(256), 0, stream, Wb_, ld, lup, Wbf, Bld, Ub);
  hipLaunchKernelGGL(moe_prep_h, dim3(1024), dim3(256), 0, stream, x, Bld, hb, xb);
  hipLaunchKernelGGL(moe_gate3,  dim3(1024), dim3(256), 0, stream, x, gW, gb, hb, cd);
  hipLaunchKernelGGL(moe_gemm_t, dim3(1024), dim3(256), 0, stream,
                     xb, Wbf, cd, Ub, bb, (float*)d_out);
}